// Round 1
// baseline (7210.948 us; speedup 1.0000x reference)
//
#include <hip/hip_runtime.h>
#include <hip/hip_bf16.h>

#define NN 50000
#define EE 800000
#define HF 96   // feature/hidden dim
#define GG 64

// ---------------- degree counts ----------------
__global__ void count_kernel(const int* __restrict__ ei, int* __restrict__ cnt_dst,
                             int* __restrict__ cnt_src, int E) {
    int e = blockIdx.x * blockDim.x + threadIdx.x;
    if (e >= E) return;
    int src = ei[e];
    int dst = ei[E + e];
    atomicAdd(&cnt_dst[dst], 1);
    atomicAdd(&cnt_src[src], 1);
}

// ---------------- scatter-add both directions ----------------
// one thread per (edge, quad-of-4-features): 24 quads per edge
__global__ void scatter_kernel(const float* __restrict__ x, const int* __restrict__ ei,
                               float* __restrict__ agg_sd, float* __restrict__ agg_ds, int E) {
    long long tid = (long long)blockIdx.x * blockDim.x + threadIdx.x;
    int e = (int)(tid / 24);
    if (e >= E) return;
    int q = (int)(tid % 24);
    int src = ei[e];
    int dst = ei[E + e];
    const float4 xs = *(const float4*)(x + (long long)src * HF + q * 4);
    const float4 xd = *(const float4*)(x + (long long)dst * HF + q * 4);
    float* psd = agg_sd + (long long)dst * HF + q * 4;
    float* pds = agg_ds + (long long)src * HF + q * 4;
    atomicAdd(psd + 0, xs.x); atomicAdd(psd + 1, xs.y);
    atomicAdd(psd + 2, xs.z); atomicAdd(psd + 3, xs.w);
    atomicAdd(pds + 0, xd.x); atomicAdd(pds + 1, xd.y);
    atomicAdd(pds + 2, xd.z); atomicAdd(pds + 3, xd.w);
}

// ---------------- fused sage: out = relu(x@Wself + bself + 0.5*(mean_sd@Wsd + bsd) + 0.5*(mean_ds@Wds + bds)) ----------------
// one thread per (node, out_feature)
__global__ __launch_bounds__(256) void sage_kernel(
        const float* __restrict__ x, const float* __restrict__ agg_sd,
        const float* __restrict__ agg_ds, const int* __restrict__ cnt_dst,
        const int* __restrict__ cnt_src,
        const float* __restrict__ Wself, const float* __restrict__ Wsd,
        const float* __restrict__ Wds,
        const float* __restrict__ bself, const float* __restrict__ bsd,
        const float* __restrict__ bds,
        float* __restrict__ out, int N) {
    long long tid = (long long)blockIdx.x * blockDim.x + threadIdx.x;
    if (tid >= (long long)N * HF) return;
    int n = (int)(tid / HF);
    int j = (int)(tid % HF);
    const float* xr = x + (long long)n * HF;
    const float* sr = agg_sd + (long long)n * HF;
    const float* dr = agg_ds + (long long)n * HF;
    const float* w0 = Wself + j;
    const float* w1 = Wsd + j;
    const float* w2 = Wds + j;
    float a0 = 0.f, a1 = 0.f, a2 = 0.f;
#pragma unroll 8
    for (int k = 0; k < HF; k++) {
        a0 = fmaf(xr[k], w0[k * HF], a0);
        a1 = fmaf(sr[k], w1[k * HF], a1);
        a2 = fmaf(dr[k], w2[k * HF], a2);
    }
    float inv_sd = 1.0f / fmaxf((float)cnt_dst[n], 1.0f);
    float inv_ds = 1.0f / fmaxf((float)cnt_src[n], 1.0f);
    float v = (a0 + bself[j]) + 0.5f * (a1 * inv_sd + bsd[j]) + 0.5f * (a2 * inv_ds + bds[j]);
    out[tid] = fmaxf(v, 0.0f);
}

// ---------------- segment max pool (batch sorted) ----------------
// blockDim = 128, threads 0..95 active (feature j); block handles CHUNK nodes
#define POOL_CHUNK 128
__global__ void pool_kernel(const float* __restrict__ h, const int* __restrict__ batch,
                            unsigned* __restrict__ g, int N) {
    int j = threadIdx.x;
    if (j >= HF) return;
    int n0 = blockIdx.x * POOL_CHUNK;
    int end = n0 + POOL_CHUNK;
    if (end > N) end = N;
    float cur = 0.0f;
    int curb = -1;
    for (int n = n0; n < end; n++) {
        int b = batch[n];
        float v = h[(long long)n * HF + j];
        if (b != curb) {
            if (curb >= 0) atomicMax(&g[curb * HF + j], __float_as_uint(cur));
            curb = b;
            cur = v;
        } else {
            cur = fmaxf(cur, v);
        }
    }
    if (curb >= 0) atomicMax(&g[curb * HF + j], __float_as_uint(cur));
}

// ---------------- final MLP: relu(g@lin1_w + lin1_b) @ lin2_w + lin2_b ----------------
__global__ void mlp_kernel(const unsigned* __restrict__ g, const float* __restrict__ lin1_w,
                           const float* __restrict__ lin1_b, const float* __restrict__ lin2_w,
                           const float* __restrict__ lin2_b, float* __restrict__ out) {
    int gi = threadIdx.x;
    if (gi >= GG) return;
    float h5[5];
#pragma unroll
    for (int hh = 0; hh < 5; hh++) {
        float acc = lin1_b[hh];
#pragma unroll 8
        for (int k = 0; k < HF; k++)
            acc = fmaf(__uint_as_float(g[gi * HF + k]), lin1_w[k * 5 + hh], acc);
        h5[hh] = fmaxf(acc, 0.0f);
    }
    float o = lin2_b[0];
#pragma unroll
    for (int hh = 0; hh < 5; hh++) o = fmaf(h5[hh], lin2_w[hh * 1 + 0], o);
    out[gi] = o;
}

extern "C" void kernel_launch(void* const* d_in, const int* in_sizes, int n_in,
                              void* d_out, int out_size, void* d_ws, size_t ws_size,
                              hipStream_t stream) {
    const float* x        = (const float*)d_in[0];
    const int*   ei       = (const int*)d_in[1];
    const int*   batch    = (const int*)d_in[2];
    // per layer: Wself, Wsd, Wds, bself, bsd, bds  (indices 3..20)
    const float* W[3][3];
    const float* B[3][3];
    for (int l = 0; l < 3; l++) {
        for (int t = 0; t < 3; t++) W[l][t] = (const float*)d_in[3 + l * 6 + t];
        for (int t = 0; t < 3; t++) B[l][t] = (const float*)d_in[3 + l * 6 + 3 + t];
    }
    const float* lin1_w = (const float*)d_in[21];
    const float* lin1_b = (const float*)d_in[22];
    const float* lin2_w = (const float*)d_in[23];
    const float* lin2_b = (const float*)d_in[24];

    const int N = in_sizes[0] / HF;
    const int E = in_sizes[1] / 2;

    // workspace layout
    float* hA      = (float*)d_ws;
    float* hB      = hA + (long long)N * HF;
    float* agg_sd  = hB + (long long)N * HF;
    float* agg_ds  = agg_sd + (long long)N * HF;
    int*   cnt_dst = (int*)(agg_ds + (long long)N * HF);
    int*   cnt_src = cnt_dst + N;
    unsigned* g    = (unsigned*)(cnt_src + N);

    // zero counts + pool output
    hipMemsetAsync(cnt_dst, 0, (size_t)2 * N * sizeof(int), stream);
    hipMemsetAsync(g, 0, (size_t)GG * HF * sizeof(unsigned), stream);

    count_kernel<<<(E + 255) / 256, 256, 0, stream>>>(ei, cnt_dst, cnt_src, E);

    const long long scatter_threads = (long long)E * 24;
    const int scatter_blocks = (int)((scatter_threads + 255) / 256);
    const long long sage_threads = (long long)N * HF;
    const int sage_blocks = (int)((sage_threads + 255) / 256);
    const int pool_blocks = (N + POOL_CHUNK - 1) / POOL_CHUNK;

    const float* cur_in = x;
    float* outs[3] = { hA, hB, hA };
    for (int l = 0; l < 3; l++) {
        hipMemsetAsync(agg_sd, 0, (size_t)2 * N * HF * sizeof(float), stream);
        scatter_kernel<<<scatter_blocks, 256, 0, stream>>>(cur_in, ei, agg_sd, agg_ds, E);
        sage_kernel<<<sage_blocks, 256, 0, stream>>>(
            cur_in, agg_sd, agg_ds, cnt_dst, cnt_src,
            W[l][0], W[l][1], W[l][2], B[l][0], B[l][1], B[l][2],
            outs[l], N);
        cur_in = outs[l];
    }

    pool_kernel<<<pool_blocks, 128, 0, stream>>>(outs[2], batch, g, N);
    mlp_kernel<<<1, 64, 0, stream>>>(g, lin1_w, lin1_b, lin2_w, lin2_b, (float*)d_out);
}

// Round 2
// 1650.095 us; speedup vs baseline: 4.3700x; 4.3700x over previous
//
#include <hip/hip_runtime.h>
#include <hip/hip_bf16.h>

#define HF 96   // feature/hidden dim
#define GG 64

// ---------------- degree counts ----------------
__global__ void count_kernel(const int* __restrict__ ei, int* __restrict__ cnt_dst,
                             int* __restrict__ cnt_src, int E) {
    int e = blockIdx.x * blockDim.x + threadIdx.x;
    if (e >= E) return;
    int src = ei[e];
    int dst = ei[E + e];
    atomicAdd(&cnt_dst[dst], 1);
    atomicAdd(&cnt_src[src], 1);
}

// ---------------- exclusive prefix scan (2 blocks: one per direction) ----------------
__global__ __launch_bounds__(1024) void scan_kernel(const int* __restrict__ cnt0,
                                                    const int* __restrict__ cnt1,
                                                    int* __restrict__ off0,
                                                    int* __restrict__ off1, int N) {
    const int* cnt = blockIdx.x ? cnt1 : cnt0;
    int* off = blockIdx.x ? off1 : off0;
    __shared__ int buf[1024];
    __shared__ int carry_s;
    if (threadIdx.x == 0) carry_s = 0;
    __syncthreads();
    for (int base = 0; base < N; base += 1024) {
        int carry = carry_s;
        int i = base + threadIdx.x;
        int v = (i < N) ? cnt[i] : 0;
        buf[threadIdx.x] = v;
        __syncthreads();
        // Hillis-Steele inclusive scan
        for (int s = 1; s < 1024; s <<= 1) {
            int t = (threadIdx.x >= s) ? buf[threadIdx.x - s] : 0;
            __syncthreads();
            buf[threadIdx.x] += t;
            __syncthreads();
        }
        int inc = buf[threadIdx.x];
        if (i < N) off[i] = carry + (inc - v);
        __syncthreads();
        if (threadIdx.x == 0) carry_s = carry + buf[1023];
        __syncthreads();
    }
    if (threadIdx.x == 0) off[N] = carry_s;
}

// ---------------- CSR fill ----------------
__global__ void fill_kernel(const int* __restrict__ ei, const int* __restrict__ off_dst,
                            const int* __restrict__ off_src, int* __restrict__ cur_dst,
                            int* __restrict__ cur_src, int* __restrict__ nbr_dst,
                            int* __restrict__ nbr_src, int E) {
    int e = blockIdx.x * blockDim.x + threadIdx.x;
    if (e >= E) return;
    int s = ei[e];
    int d = ei[E + e];
    int p = atomicAdd(&cur_dst[d], 1);
    nbr_dst[off_dst[d] + p] = s;
    int q = atomicAdd(&cur_src[s], 1);
    nbr_src[off_src[s] + q] = d;
}

// ---------------- gather-mean, both directions ----------------
// one thread per (node, float4-quad): 24 quads per node
__global__ __launch_bounds__(256) void gather_kernel(
        const float* __restrict__ x,
        const int* __restrict__ off_dst, const int* __restrict__ nbr_dst,
        const int* __restrict__ off_src, const int* __restrict__ nbr_src,
        float* __restrict__ agg_sd, float* __restrict__ agg_ds, int N) {
    int t = blockIdx.x * blockDim.x + threadIdx.x;
    int n = t / 24;
    if (n >= N) return;
    int q = t % 24;

    // source_to_target: mean of x[src] over in-edges at dst=n
    {
        int b = off_dst[n], e2 = off_dst[n + 1];
        float4 acc = make_float4(0.f, 0.f, 0.f, 0.f);
        for (int i = b; i < e2; i++) {
            int nb = nbr_dst[i];
            const float4 v = *(const float4*)(x + (long long)nb * HF + q * 4);
            acc.x += v.x; acc.y += v.y; acc.z += v.z; acc.w += v.w;
        }
        float inv = 1.0f / fmaxf((float)(e2 - b), 1.0f);
        acc.x *= inv; acc.y *= inv; acc.z *= inv; acc.w *= inv;
        *(float4*)(agg_sd + (long long)n * HF + q * 4) = acc;
    }
    // target_to_source: mean of x[dst] over out-edges at src=n
    {
        int b = off_src[n], e2 = off_src[n + 1];
        float4 acc = make_float4(0.f, 0.f, 0.f, 0.f);
        for (int i = b; i < e2; i++) {
            int nb = nbr_src[i];
            const float4 v = *(const float4*)(x + (long long)nb * HF + q * 4);
            acc.x += v.x; acc.y += v.y; acc.z += v.z; acc.w += v.w;
        }
        float inv = 1.0f / fmaxf((float)(e2 - b), 1.0f);
        acc.x *= inv; acc.y *= inv; acc.z *= inv; acc.w *= inv;
        *(float4*)(agg_ds + (long long)n * HF + q * 4) = acc;
    }
}

// ---------------- fused sage: out = relu(x@Wself + bself + 0.5*(mean_sd@Wsd + bsd) + 0.5*(mean_ds@Wds + bds)) ----------------
// one thread per (node, out_feature); agg buffers already hold means
__global__ __launch_bounds__(256) void sage_kernel(
        const float* __restrict__ x, const float* __restrict__ agg_sd,
        const float* __restrict__ agg_ds,
        const float* __restrict__ Wself, const float* __restrict__ Wsd,
        const float* __restrict__ Wds,
        const float* __restrict__ bself, const float* __restrict__ bsd,
        const float* __restrict__ bds,
        float* __restrict__ out, int N) {
    long long tid = (long long)blockIdx.x * blockDim.x + threadIdx.x;
    if (tid >= (long long)N * HF) return;
    int n = (int)(tid / HF);
    int j = (int)(tid % HF);
    const float* xr = x + (long long)n * HF;
    const float* sr = agg_sd + (long long)n * HF;
    const float* dr = agg_ds + (long long)n * HF;
    const float* w0 = Wself + j;
    const float* w1 = Wsd + j;
    const float* w2 = Wds + j;
    float a0 = 0.f, a1 = 0.f, a2 = 0.f;
#pragma unroll 8
    for (int k = 0; k < HF; k++) {
        a0 = fmaf(xr[k], w0[k * HF], a0);
        a1 = fmaf(sr[k], w1[k * HF], a1);
        a2 = fmaf(dr[k], w2[k * HF], a2);
    }
    float v = (a0 + bself[j]) + 0.5f * (a1 + bsd[j]) + 0.5f * (a2 + bds[j]);
    out[tid] = fmaxf(v, 0.0f);
}

// ---------------- segment max pool (batch sorted) ----------------
#define POOL_CHUNK 128
__global__ void pool_kernel(const float* __restrict__ h, const int* __restrict__ batch,
                            unsigned* __restrict__ g, int N) {
    int j = threadIdx.x;
    if (j >= HF) return;
    int n0 = blockIdx.x * POOL_CHUNK;
    int end = n0 + POOL_CHUNK;
    if (end > N) end = N;
    float cur = 0.0f;
    int curb = -1;
    for (int n = n0; n < end; n++) {
        int b = batch[n];
        float v = h[(long long)n * HF + j];
        if (b != curb) {
            if (curb >= 0) atomicMax(&g[curb * HF + j], __float_as_uint(cur));
            curb = b;
            cur = v;
        } else {
            cur = fmaxf(cur, v);
        }
    }
    if (curb >= 0) atomicMax(&g[curb * HF + j], __float_as_uint(cur));
}

// ---------------- final MLP ----------------
__global__ void mlp_kernel(const unsigned* __restrict__ g, const float* __restrict__ lin1_w,
                           const float* __restrict__ lin1_b, const float* __restrict__ lin2_w,
                           const float* __restrict__ lin2_b, float* __restrict__ out) {
    int gi = threadIdx.x;
    if (gi >= GG) return;
    float h5[5];
#pragma unroll
    for (int hh = 0; hh < 5; hh++) {
        float acc = lin1_b[hh];
#pragma unroll 8
        for (int k = 0; k < HF; k++)
            acc = fmaf(__uint_as_float(g[gi * HF + k]), lin1_w[k * 5 + hh], acc);
        h5[hh] = fmaxf(acc, 0.0f);
    }
    float o = lin2_b[0];
#pragma unroll
    for (int hh = 0; hh < 5; hh++) o = fmaf(h5[hh], lin2_w[hh * 1 + 0], o);
    out[gi] = o;
}

extern "C" void kernel_launch(void* const* d_in, const int* in_sizes, int n_in,
                              void* d_out, int out_size, void* d_ws, size_t ws_size,
                              hipStream_t stream) {
    const float* x     = (const float*)d_in[0];
    const int*   ei    = (const int*)d_in[1];
    const int*   batch = (const int*)d_in[2];
    const float* W[3][3];
    const float* B[3][3];
    for (int l = 0; l < 3; l++) {
        for (int t = 0; t < 3; t++) W[l][t] = (const float*)d_in[3 + l * 6 + t];
        for (int t = 0; t < 3; t++) B[l][t] = (const float*)d_in[3 + l * 6 + 3 + t];
    }
    const float* lin1_w = (const float*)d_in[21];
    const float* lin1_b = (const float*)d_in[22];
    const float* lin2_w = (const float*)d_in[23];
    const float* lin2_b = (const float*)d_in[24];

    const int N = in_sizes[0] / HF;
    const int E = in_sizes[1] / 2;

    // workspace layout
    float* hA      = (float*)d_ws;
    float* hB      = hA + (long long)N * HF;
    float* agg_sd  = hB + (long long)N * HF;
    float* agg_ds  = agg_sd + (long long)N * HF;
    int*   cnt_dst = (int*)(agg_ds + (long long)N * HF);
    int*   cnt_src = cnt_dst + N;
    int*   off_dst = cnt_src + N;           // N+1
    int*   off_src = off_dst + (N + 1);     // N+1
    int*   cur_dst = off_src + (N + 1);
    int*   cur_src = cur_dst + N;
    int*   nbr_dst = cur_src + N;           // E
    int*   nbr_src = nbr_dst + E;           // E
    unsigned* g    = (unsigned*)(nbr_src + E);

    // zero counts, cursors, pool output
    hipMemsetAsync(cnt_dst, 0, (size_t)2 * N * sizeof(int), stream);
    hipMemsetAsync(cur_dst, 0, (size_t)2 * N * sizeof(int), stream);
    hipMemsetAsync(g, 0, (size_t)GG * HF * sizeof(unsigned), stream);

    // build CSR (both directions) once per call
    count_kernel<<<(E + 255) / 256, 256, 0, stream>>>(ei, cnt_dst, cnt_src, E);
    scan_kernel<<<2, 1024, 0, stream>>>(cnt_dst, cnt_src, off_dst, off_src, N);
    fill_kernel<<<(E + 255) / 256, 256, 0, stream>>>(ei, off_dst, off_src,
                                                     cur_dst, cur_src, nbr_dst, nbr_src, E);

    const long long gather_threads = (long long)N * 24;
    const int gather_blocks = (int)((gather_threads + 255) / 256);
    const long long sage_threads = (long long)N * HF;
    const int sage_blocks = (int)((sage_threads + 255) / 256);
    const int pool_blocks = (N + POOL_CHUNK - 1) / POOL_CHUNK;

    const float* cur_in = x;
    float* outs[3] = { hA, hB, hA };
    for (int l = 0; l < 3; l++) {
        gather_kernel<<<gather_blocks, 256, 0, stream>>>(
            cur_in, off_dst, nbr_dst, off_src, nbr_src, agg_sd, agg_ds, N);
        sage_kernel<<<sage_blocks, 256, 0, stream>>>(
            cur_in, agg_sd, agg_ds,
            W[l][0], W[l][1], W[l][2], B[l][0], B[l][1], B[l][2],
            outs[l], N);
        cur_in = outs[l];
    }

    pool_kernel<<<pool_blocks, 128, 0, stream>>>(outs[2], batch, g, N);
    mlp_kernel<<<1, 64, 0, stream>>>(g, lin1_w, lin1_b, lin2_w, lin2_b, (float*)d_out);
}

// Round 3
// 825.938 us; speedup vs baseline: 8.7306x; 1.9978x over previous
//
#include <hip/hip_runtime.h>
#include <hip/hip_bf16.h>

#define HF 96   // feature/hidden dim
#define GG 64

// ---------------- degree counts ----------------
__global__ void count_kernel(const int* __restrict__ ei, int* __restrict__ cnt_dst,
                             int* __restrict__ cnt_src, int E) {
    int e = blockIdx.x * blockDim.x + threadIdx.x;
    if (e >= E) return;
    int src = ei[e];
    int dst = ei[E + e];
    atomicAdd(&cnt_dst[dst], 1);
    atomicAdd(&cnt_src[src], 1);
}

// ---------------- exclusive prefix scan (2 blocks: one per direction) ----------------
__global__ __launch_bounds__(1024) void scan_kernel(const int* __restrict__ cnt0,
                                                    const int* __restrict__ cnt1,
                                                    int* __restrict__ off0,
                                                    int* __restrict__ off1, int N) {
    const int* cnt = blockIdx.x ? cnt1 : cnt0;
    int* off = blockIdx.x ? off1 : off0;
    __shared__ int buf[1024];
    __shared__ int carry_s;
    if (threadIdx.x == 0) carry_s = 0;
    __syncthreads();
    for (int base = 0; base < N; base += 1024) {
        int carry = carry_s;
        int i = base + threadIdx.x;
        int v = (i < N) ? cnt[i] : 0;
        buf[threadIdx.x] = v;
        __syncthreads();
        for (int s = 1; s < 1024; s <<= 1) {
            int t = (threadIdx.x >= s) ? buf[threadIdx.x - s] : 0;
            __syncthreads();
            buf[threadIdx.x] += t;
            __syncthreads();
        }
        int inc = buf[threadIdx.x];
        if (i < N) off[i] = carry + (inc - v);
        __syncthreads();
        if (threadIdx.x == 0) carry_s = carry + buf[1023];
        __syncthreads();
    }
    if (threadIdx.x == 0) off[N] = carry_s;
}

// ---------------- CSR fill ----------------
__global__ void fill_kernel(const int* __restrict__ ei, const int* __restrict__ off_dst,
                            const int* __restrict__ off_src, int* __restrict__ cur_dst,
                            int* __restrict__ cur_src, int* __restrict__ nbr_dst,
                            int* __restrict__ nbr_src, int E) {
    int e = blockIdx.x * blockDim.x + threadIdx.x;
    if (e >= E) return;
    int s = ei[e];
    int d = ei[E + e];
    int p = atomicAdd(&cur_dst[d], 1);
    nbr_dst[off_dst[d] + p] = s;
    int q = atomicAdd(&cur_src[s], 1);
    nbr_src[off_src[s] + q] = d;
}

// ---------------- gather-mean (x0.5 ALPHA folded), both directions ----------------
// one thread per (node, float4-quad): 24 quads per node
__global__ __launch_bounds__(256) void gather_kernel(
        const float* __restrict__ x,
        const int* __restrict__ off_dst, const int* __restrict__ nbr_dst,
        const int* __restrict__ off_src, const int* __restrict__ nbr_src,
        float* __restrict__ agg_sd, float* __restrict__ agg_ds, int N) {
    int t = blockIdx.x * blockDim.x + threadIdx.x;
    int n = t / 24;
    if (n >= N) return;
    int q = t % 24;

    {
        int b = off_dst[n], e2 = off_dst[n + 1];
        float4 acc = make_float4(0.f, 0.f, 0.f, 0.f);
        for (int i = b; i < e2; i++) {
            int nb = nbr_dst[i];
            const float4 v = *(const float4*)(x + (long long)nb * HF + q * 4);
            acc.x += v.x; acc.y += v.y; acc.z += v.z; acc.w += v.w;
        }
        float inv = 0.5f / fmaxf((float)(e2 - b), 1.0f);   // ALPHA=0.5 folded (exact pow2 scale)
        acc.x *= inv; acc.y *= inv; acc.z *= inv; acc.w *= inv;
        *(float4*)(agg_sd + (long long)n * HF + q * 4) = acc;
    }
    {
        int b = off_src[n], e2 = off_src[n + 1];
        float4 acc = make_float4(0.f, 0.f, 0.f, 0.f);
        for (int i = b; i < e2; i++) {
            int nb = nbr_src[i];
            const float4 v = *(const float4*)(x + (long long)nb * HF + q * 4);
            acc.x += v.x; acc.y += v.y; acc.z += v.z; acc.w += v.w;
        }
        float inv = 0.5f / fmaxf((float)(e2 - b), 1.0f);
        acc.x *= inv; acc.y *= inv; acc.z *= inv; acc.w *= inv;
        *(float4*)(agg_ds + (long long)n * HF + q * 4) = acc;
    }
}

// ---------------- tiled sage GEMM ----------------
// C[N x 96] = relu( [x | agg_sd | agg_ds] (N x 288) @ [Wself;Wsd;Wds] (288 x 96) + bcomb )
// BM=64 rows/block, BK=32, 256 threads; thread computes 2 rows x 12 cols.
#define BM 64
#define BK 32
#define ASTR 36    // 32 + 4 pad (16B-aligned rows, 2-way-at-most read conflicts = free)
#define WSTR 100   // 96 + 4 pad
__global__ __launch_bounds__(256) void sage_gemm_kernel(
        const float* __restrict__ x, const float* __restrict__ agg_sd,
        const float* __restrict__ agg_ds,
        const float* __restrict__ Wself, const float* __restrict__ Wsd,
        const float* __restrict__ Wds,
        const float* __restrict__ bself, const float* __restrict__ bsd,
        const float* __restrict__ bds,
        float* __restrict__ out, int N) {
    __shared__ float As[BM * ASTR];
    __shared__ float Wsh[BK * WSTR];

    const int tx = threadIdx.x;
    const int rowg = tx >> 3;      // 0..31 -> rows rowg*2, rowg*2+1
    const int colg = tx & 7;       // 0..7  -> cols colg*12 .. +11
    const int row0 = blockIdx.x * BM;

    float acc[2][12];
#pragma unroll
    for (int i = 0; i < 2; i++)
#pragma unroll
        for (int c = 0; c < 12; c++) acc[i][c] = 0.f;

    for (int kt = 0; kt < 9; kt++) {
        const float* A = (kt < 3) ? x : (kt < 6) ? agg_sd : agg_ds;
        const float* W = (kt < 3) ? Wself : (kt < 6) ? Wsd : Wds;
        const int koff = (kt % 3) * BK;

        // stage A: 64x32 tile = 512 float4, 2 per thread
#pragma unroll
        for (int i = 0; i < 2; i++) {
            int f4 = tx + 256 * i;
            int r = f4 >> 3;        // 0..63
            int kq = f4 & 7;        // 0..7
            int rg = row0 + r; if (rg > N - 1) rg = N - 1;
            float4 v = *(const float4*)(A + (long long)rg * HF + koff + kq * 4);
            *(float4*)(&As[r * ASTR + kq * 4]) = v;
        }
        // stage W: 32x96 tile = 768 float4, 3 per thread
#pragma unroll
        for (int i = 0; i < 3; i++) {
            int f4 = tx + 256 * i;
            int k = f4 / 24;
            int jq = f4 - k * 24;
            float4 v = *(const float4*)(W + (long long)(koff + k) * HF + jq * 4);
            *(float4*)(&Wsh[k * WSTR + jq * 4]) = v;
        }
        __syncthreads();

#pragma unroll 4
        for (int k = 0; k < BK; k++) {
            float a0 = As[(rowg * 2 + 0) * ASTR + k];
            float a1 = As[(rowg * 2 + 1) * ASTR + k];
            float4 w0 = *(const float4*)(&Wsh[k * WSTR + colg * 12 + 0]);
            float4 w1 = *(const float4*)(&Wsh[k * WSTR + colg * 12 + 4]);
            float4 w2 = *(const float4*)(&Wsh[k * WSTR + colg * 12 + 8]);
            acc[0][0]  = fmaf(a0, w0.x, acc[0][0]);
            acc[0][1]  = fmaf(a0, w0.y, acc[0][1]);
            acc[0][2]  = fmaf(a0, w0.z, acc[0][2]);
            acc[0][3]  = fmaf(a0, w0.w, acc[0][3]);
            acc[0][4]  = fmaf(a0, w1.x, acc[0][4]);
            acc[0][5]  = fmaf(a0, w1.y, acc[0][5]);
            acc[0][6]  = fmaf(a0, w1.z, acc[0][6]);
            acc[0][7]  = fmaf(a0, w1.w, acc[0][7]);
            acc[0][8]  = fmaf(a0, w2.x, acc[0][8]);
            acc[0][9]  = fmaf(a0, w2.y, acc[0][9]);
            acc[0][10] = fmaf(a0, w2.z, acc[0][10]);
            acc[0][11] = fmaf(a0, w2.w, acc[0][11]);
            acc[1][0]  = fmaf(a1, w0.x, acc[1][0]);
            acc[1][1]  = fmaf(a1, w0.y, acc[1][1]);
            acc[1][2]  = fmaf(a1, w0.z, acc[1][2]);
            acc[1][3]  = fmaf(a1, w0.w, acc[1][3]);
            acc[1][4]  = fmaf(a1, w1.x, acc[1][4]);
            acc[1][5]  = fmaf(a1, w1.y, acc[1][5]);
            acc[1][6]  = fmaf(a1, w1.z, acc[1][6]);
            acc[1][7]  = fmaf(a1, w1.w, acc[1][7]);
            acc[1][8]  = fmaf(a1, w2.x, acc[1][8]);
            acc[1][9]  = fmaf(a1, w2.y, acc[1][9]);
            acc[1][10] = fmaf(a1, w2.z, acc[1][10]);
            acc[1][11] = fmaf(a1, w2.w, acc[1][11]);
        }
        __syncthreads();
    }

    // epilogue: combined bias + relu + store
    const int j0 = colg * 12;
    float bc[12];
#pragma unroll
    for (int c = 0; c < 12; c++)
        bc[c] = bself[j0 + c] + 0.5f * (bsd[j0 + c] + bds[j0 + c]);
#pragma unroll
    for (int i = 0; i < 2; i++) {
        int r = row0 + rowg * 2 + i;
        if (r < N) {
            float4 o0, o1, o2;
            o0.x = fmaxf(acc[i][0]  + bc[0],  0.f);
            o0.y = fmaxf(acc[i][1]  + bc[1],  0.f);
            o0.z = fmaxf(acc[i][2]  + bc[2],  0.f);
            o0.w = fmaxf(acc[i][3]  + bc[3],  0.f);
            o1.x = fmaxf(acc[i][4]  + bc[4],  0.f);
            o1.y = fmaxf(acc[i][5]  + bc[5],  0.f);
            o1.z = fmaxf(acc[i][6]  + bc[6],  0.f);
            o1.w = fmaxf(acc[i][7]  + bc[7],  0.f);
            o2.x = fmaxf(acc[i][8]  + bc[8],  0.f);
            o2.y = fmaxf(acc[i][9]  + bc[9],  0.f);
            o2.z = fmaxf(acc[i][10] + bc[10], 0.f);
            o2.w = fmaxf(acc[i][11] + bc[11], 0.f);
            float* po = out + (long long)r * HF + j0;
            *(float4*)(po + 0) = o0;
            *(float4*)(po + 4) = o1;
            *(float4*)(po + 8) = o2;
        }
    }
}

// ---------------- segment max pool (batch sorted) ----------------
#define POOL_CHUNK 128
__global__ void pool_kernel(const float* __restrict__ h, const int* __restrict__ batch,
                            unsigned* __restrict__ g, int N) {
    int j = threadIdx.x;
    if (j >= HF) return;
    int n0 = blockIdx.x * POOL_CHUNK;
    int end = n0 + POOL_CHUNK;
    if (end > N) end = N;
    float cur = 0.0f;
    int curb = -1;
    for (int n = n0; n < end; n++) {
        int b = batch[n];
        float v = h[(long long)n * HF + j];
        if (b != curb) {
            if (curb >= 0) atomicMax(&g[curb * HF + j], __float_as_uint(cur));
            curb = b;
            cur = v;
        } else {
            cur = fmaxf(cur, v);
        }
    }
    if (curb >= 0) atomicMax(&g[curb * HF + j], __float_as_uint(cur));
}

// ---------------- final MLP ----------------
__global__ void mlp_kernel(const unsigned* __restrict__ g, const float* __restrict__ lin1_w,
                           const float* __restrict__ lin1_b, const float* __restrict__ lin2_w,
                           const float* __restrict__ lin2_b, float* __restrict__ out) {
    int gi = threadIdx.x;
    if (gi >= GG) return;
    float h5[5];
#pragma unroll
    for (int hh = 0; hh < 5; hh++) {
        float acc = lin1_b[hh];
#pragma unroll 8
        for (int k = 0; k < HF; k++)
            acc = fmaf(__uint_as_float(g[gi * HF + k]), lin1_w[k * 5 + hh], acc);
        h5[hh] = fmaxf(acc, 0.0f);
    }
    float o = lin2_b[0];
#pragma unroll
    for (int hh = 0; hh < 5; hh++) o = fmaf(h5[hh], lin2_w[hh * 1 + 0], o);
    out[gi] = o;
}

extern "C" void kernel_launch(void* const* d_in, const int* in_sizes, int n_in,
                              void* d_out, int out_size, void* d_ws, size_t ws_size,
                              hipStream_t stream) {
    const float* x     = (const float*)d_in[0];
    const int*   ei    = (const int*)d_in[1];
    const int*   batch = (const int*)d_in[2];
    const float* W[3][3];
    const float* B[3][3];
    for (int l = 0; l < 3; l++) {
        for (int t = 0; t < 3; t++) W[l][t] = (const float*)d_in[3 + l * 6 + t];
        for (int t = 0; t < 3; t++) B[l][t] = (const float*)d_in[3 + l * 6 + 3 + t];
    }
    const float* lin1_w = (const float*)d_in[21];
    const float* lin1_b = (const float*)d_in[22];
    const float* lin2_w = (const float*)d_in[23];
    const float* lin2_b = (const float*)d_in[24];

    const int N = in_sizes[0] / HF;
    const int E = in_sizes[1] / 2;

    // workspace layout
    float* hA      = (float*)d_ws;
    float* hB      = hA + (long long)N * HF;
    float* agg_sd  = hB + (long long)N * HF;
    float* agg_ds  = agg_sd + (long long)N * HF;
    int*   cnt_dst = (int*)(agg_ds + (long long)N * HF);
    int*   cnt_src = cnt_dst + N;
    int*   off_dst = cnt_src + N;           // N+1
    int*   off_src = off_dst + (N + 1);     // N+1
    int*   cur_dst = off_src + (N + 1);
    int*   cur_src = cur_dst + N;
    int*   nbr_dst = cur_src + N;           // E
    int*   nbr_src = nbr_dst + E;           // E
    unsigned* g    = (unsigned*)(nbr_src + E);

    hipMemsetAsync(cnt_dst, 0, (size_t)2 * N * sizeof(int), stream);
    hipMemsetAsync(cur_dst, 0, (size_t)2 * N * sizeof(int), stream);
    hipMemsetAsync(g, 0, (size_t)GG * HF * sizeof(unsigned), stream);

    count_kernel<<<(E + 255) / 256, 256, 0, stream>>>(ei, cnt_dst, cnt_src, E);
    scan_kernel<<<2, 1024, 0, stream>>>(cnt_dst, cnt_src, off_dst, off_src, N);
    fill_kernel<<<(E + 255) / 256, 256, 0, stream>>>(ei, off_dst, off_src,
                                                     cur_dst, cur_src, nbr_dst, nbr_src, E);

    const long long gather_threads = (long long)N * 24;
    const int gather_blocks = (int)((gather_threads + 255) / 256);
    const int gemm_blocks = (N + BM - 1) / BM;
    const int pool_blocks = (N + POOL_CHUNK - 1) / POOL_CHUNK;

    const float* cur_in = x;
    float* outs[3] = { hA, hB, hA };
    for (int l = 0; l < 3; l++) {
        gather_kernel<<<gather_blocks, 256, 0, stream>>>(
            cur_in, off_dst, nbr_dst, off_src, nbr_src, agg_sd, agg_ds, N);
        sage_gemm_kernel<<<gemm_blocks, 256, 0, stream>>>(
            cur_in, agg_sd, agg_ds,
            W[l][0], W[l][1], W[l][2], B[l][0], B[l][1], B[l][2],
            outs[l], N);
        cur_in = outs[l];
    }

    pool_kernel<<<pool_blocks, 128, 0, stream>>>(outs[2], batch, g, N);
    mlp_kernel<<<1, 64, 0, stream>>>(g, lin1_w, lin1_b, lin2_w, lin2_b, (float*)d_out);
}

// Round 4
// 705.815 us; speedup vs baseline: 10.2165x; 1.1702x over previous
//
#include <hip/hip_runtime.h>
#include <hip/hip_bf16.h>

#define HF 96   // feature/hidden dim
#define GG 64
#define SB 64   // scan blocks per direction

// ---------------- degree counts ----------------
__global__ void count_kernel(const int* __restrict__ ei, int* __restrict__ cnt_dst,
                             int* __restrict__ cnt_src, int E) {
    int e = blockIdx.x * blockDim.x + threadIdx.x;
    if (e >= E) return;
    int src = ei[e];
    int dst = ei[E + e];
    atomicAdd(&cnt_dst[dst], 1);
    atomicAdd(&cnt_src[src], 1);
}

// ---------------- 3-phase exclusive scan ----------------
__global__ __launch_bounds__(256) void scan_phase1(const int* __restrict__ cnt0,
                                                   const int* __restrict__ cnt1,
                                                   int* __restrict__ off0,
                                                   int* __restrict__ off1,
                                                   int* __restrict__ bsum, int N, int CH) {
    int dir = blockIdx.y;
    const int* cnt = dir ? cnt1 : cnt0;
    int* off = dir ? off1 : off0;
    int base = blockIdx.x * CH;
    int end = base + CH; if (end > N) end = N;
    __shared__ int buf[256];
    int carry = 0;
    for (int s = base; s < end; s += 256) {
        int i = s + threadIdx.x;
        int v = (i < end) ? cnt[i] : 0;
        buf[threadIdx.x] = v;
        __syncthreads();
        for (int st = 1; st < 256; st <<= 1) {
            int tv = (threadIdx.x >= st) ? buf[threadIdx.x - st] : 0;
            __syncthreads();
            buf[threadIdx.x] += tv;
            __syncthreads();
        }
        if (i < end) off[i] = carry + buf[threadIdx.x] - v;
        carry += buf[255];
        __syncthreads();
    }
    if (threadIdx.x == 0) bsum[dir * SB + blockIdx.x] = carry;
}

__global__ __launch_bounds__(64) void scan_phase2(int* __restrict__ bsum, int* __restrict__ boff,
                                                  int* __restrict__ off0, int* __restrict__ off1,
                                                  int N) {
    int dir = blockIdx.x;
    __shared__ int buf[SB];
    int v = bsum[dir * SB + threadIdx.x];
    buf[threadIdx.x] = v;
    __syncthreads();
    for (int st = 1; st < SB; st <<= 1) {
        int tv = (threadIdx.x >= st) ? buf[threadIdx.x - st] : 0;
        __syncthreads();
        buf[threadIdx.x] += tv;
        __syncthreads();
    }
    boff[dir * SB + threadIdx.x] = buf[threadIdx.x] - v;  // exclusive block offset
    if (threadIdx.x == SB - 1) {
        int* off = dir ? off1 : off0;
        off[N] = buf[SB - 1];
    }
}

__global__ void scan_phase3(int* __restrict__ off0, int* __restrict__ off1,
                            const int* __restrict__ boff, int N, int CH) {
    int dir = blockIdx.y;
    int* off = dir ? off1 : off0;
    int i = blockIdx.x * 256 + threadIdx.x;
    if (i >= N) return;
    off[i] += boff[dir * SB + i / CH];
}

// ---------------- CSR fill ----------------
__global__ void fill_kernel(const int* __restrict__ ei, const int* __restrict__ off_dst,
                            const int* __restrict__ off_src, int* __restrict__ cur_dst,
                            int* __restrict__ cur_src, int* __restrict__ nbr_dst,
                            int* __restrict__ nbr_src, int E) {
    int e = blockIdx.x * blockDim.x + threadIdx.x;
    if (e >= E) return;
    int s = ei[e];
    int d = ei[E + e];
    int p = atomicAdd(&cur_dst[d], 1);
    nbr_dst[off_dst[d] + p] = s;
    int q = atomicAdd(&cur_src[s], 1);
    nbr_src[off_src[s] + q] = d;
}

// ---------------- gather-mean (x0.5 ALPHA folded), direction-split, 4-way unrolled ----------------
// one thread per (direction, node, float4-quad): 2*N*24 threads
__global__ __launch_bounds__(256) void gather_kernel(
        const float* __restrict__ x,
        const int* __restrict__ off_dst, const int* __restrict__ nbr_dst,
        const int* __restrict__ off_src, const int* __restrict__ nbr_src,
        float* __restrict__ agg_sd, float* __restrict__ agg_ds, int N) {
    int t = blockIdx.x * blockDim.x + threadIdx.x;
    int n2 = t / 24;
    if (n2 >= 2 * N) return;
    int q = t % 24;
    int dir = (n2 >= N) ? 1 : 0;
    int n = n2 - dir * N;
    const int* off = dir ? off_src : off_dst;
    const int* nbr = dir ? nbr_src : nbr_dst;
    float* agg = dir ? agg_ds : agg_sd;

    int b = off[n], e = off[n + 1];
    const float* xq = x + q * 4;
    float4 a0 = make_float4(0.f, 0.f, 0.f, 0.f);
    float4 a1 = make_float4(0.f, 0.f, 0.f, 0.f);
    float4 a2 = make_float4(0.f, 0.f, 0.f, 0.f);
    float4 a3 = make_float4(0.f, 0.f, 0.f, 0.f);
    int i = b;
    for (; i + 4 <= e; i += 4) {
        int i0 = nbr[i + 0], i1 = nbr[i + 1], i2 = nbr[i + 2], i3 = nbr[i + 3];
        float4 v0 = *(const float4*)(xq + (long long)i0 * HF);
        float4 v1 = *(const float4*)(xq + (long long)i1 * HF);
        float4 v2 = *(const float4*)(xq + (long long)i2 * HF);
        float4 v3 = *(const float4*)(xq + (long long)i3 * HF);
        a0.x += v0.x; a0.y += v0.y; a0.z += v0.z; a0.w += v0.w;
        a1.x += v1.x; a1.y += v1.y; a1.z += v1.z; a1.w += v1.w;
        a2.x += v2.x; a2.y += v2.y; a2.z += v2.z; a2.w += v2.w;
        a3.x += v3.x; a3.y += v3.y; a3.z += v3.z; a3.w += v3.w;
    }
    for (; i < e; i++) {
        int i0 = nbr[i];
        float4 v0 = *(const float4*)(xq + (long long)i0 * HF);
        a0.x += v0.x; a0.y += v0.y; a0.z += v0.z; a0.w += v0.w;
    }
    float4 acc;
    acc.x = (a0.x + a1.x) + (a2.x + a3.x);
    acc.y = (a0.y + a1.y) + (a2.y + a3.y);
    acc.z = (a0.z + a1.z) + (a2.z + a3.z);
    acc.w = (a0.w + a1.w) + (a2.w + a3.w);
    float inv = 0.5f / fmaxf((float)(e - b), 1.0f);   // ALPHA=0.5 folded (exact pow2 scale)
    acc.x *= inv; acc.y *= inv; acc.z *= inv; acc.w *= inv;
    *(float4*)(agg + (long long)n * HF + q * 4) = acc;
}

// ---------------- tiled sage GEMM ----------------
// C[N x 96] = relu( [x | agg_sd | agg_ds] (N x 288) @ [Wself;Wsd;Wds] (288 x 96) + bcomb )
#define BM 64
#define BK 32
#define ASTR 36
#define WSTR 100
__global__ __launch_bounds__(256) void sage_gemm_kernel(
        const float* __restrict__ x, const float* __restrict__ agg_sd,
        const float* __restrict__ agg_ds,
        const float* __restrict__ Wself, const float* __restrict__ Wsd,
        const float* __restrict__ Wds,
        const float* __restrict__ bself, const float* __restrict__ bsd,
        const float* __restrict__ bds,
        float* __restrict__ out, int N) {
    __shared__ float As[BM * ASTR];
    __shared__ float Wsh[BK * WSTR];

    const int tx = threadIdx.x;
    const int rowg = tx >> 3;
    const int colg = tx & 7;
    const int row0 = blockIdx.x * BM;

    float acc[2][12];
#pragma unroll
    for (int i = 0; i < 2; i++)
#pragma unroll
        for (int c = 0; c < 12; c++) acc[i][c] = 0.f;

    for (int kt = 0; kt < 9; kt++) {
        const float* A = (kt < 3) ? x : (kt < 6) ? agg_sd : agg_ds;
        const float* W = (kt < 3) ? Wself : (kt < 6) ? Wsd : Wds;
        const int koff = (kt % 3) * BK;

#pragma unroll
        for (int i = 0; i < 2; i++) {
            int f4 = tx + 256 * i;
            int r = f4 >> 3;
            int kq = f4 & 7;
            int rg = row0 + r; if (rg > N - 1) rg = N - 1;
            float4 v = *(const float4*)(A + (long long)rg * HF + koff + kq * 4);
            *(float4*)(&As[r * ASTR + kq * 4]) = v;
        }
#pragma unroll
        for (int i = 0; i < 3; i++) {
            int f4 = tx + 256 * i;
            int k = f4 / 24;
            int jq = f4 - k * 24;
            float4 v = *(const float4*)(W + (long long)(koff + k) * HF + jq * 4);
            *(float4*)(&Wsh[k * WSTR + jq * 4]) = v;
        }
        __syncthreads();

#pragma unroll 4
        for (int k = 0; k < BK; k++) {
            float a0 = As[(rowg * 2 + 0) * ASTR + k];
            float a1 = As[(rowg * 2 + 1) * ASTR + k];
            float4 w0 = *(const float4*)(&Wsh[k * WSTR + colg * 12 + 0]);
            float4 w1 = *(const float4*)(&Wsh[k * WSTR + colg * 12 + 4]);
            float4 w2 = *(const float4*)(&Wsh[k * WSTR + colg * 12 + 8]);
            acc[0][0]  = fmaf(a0, w0.x, acc[0][0]);
            acc[0][1]  = fmaf(a0, w0.y, acc[0][1]);
            acc[0][2]  = fmaf(a0, w0.z, acc[0][2]);
            acc[0][3]  = fmaf(a0, w0.w, acc[0][3]);
            acc[0][4]  = fmaf(a0, w1.x, acc[0][4]);
            acc[0][5]  = fmaf(a0, w1.y, acc[0][5]);
            acc[0][6]  = fmaf(a0, w1.z, acc[0][6]);
            acc[0][7]  = fmaf(a0, w1.w, acc[0][7]);
            acc[0][8]  = fmaf(a0, w2.x, acc[0][8]);
            acc[0][9]  = fmaf(a0, w2.y, acc[0][9]);
            acc[0][10] = fmaf(a0, w2.z, acc[0][10]);
            acc[0][11] = fmaf(a0, w2.w, acc[0][11]);
            acc[1][0]  = fmaf(a1, w0.x, acc[1][0]);
            acc[1][1]  = fmaf(a1, w0.y, acc[1][1]);
            acc[1][2]  = fmaf(a1, w0.z, acc[1][2]);
            acc[1][3]  = fmaf(a1, w0.w, acc[1][3]);
            acc[1][4]  = fmaf(a1, w1.x, acc[1][4]);
            acc[1][5]  = fmaf(a1, w1.y, acc[1][5]);
            acc[1][6]  = fmaf(a1, w1.z, acc[1][6]);
            acc[1][7]  = fmaf(a1, w1.w, acc[1][7]);
            acc[1][8]  = fmaf(a1, w2.x, acc[1][8]);
            acc[1][9]  = fmaf(a1, w2.y, acc[1][9]);
            acc[1][10] = fmaf(a1, w2.z, acc[1][10]);
            acc[1][11] = fmaf(a1, w2.w, acc[1][11]);
        }
        __syncthreads();
    }

    const int j0 = colg * 12;
    float bc[12];
#pragma unroll
    for (int c = 0; c < 12; c++)
        bc[c] = bself[j0 + c] + 0.5f * (bsd[j0 + c] + bds[j0 + c]);
#pragma unroll
    for (int i = 0; i < 2; i++) {
        int r = row0 + rowg * 2 + i;
        if (r < N) {
            float4 o0, o1, o2;
            o0.x = fmaxf(acc[i][0]  + bc[0],  0.f);
            o0.y = fmaxf(acc[i][1]  + bc[1],  0.f);
            o0.z = fmaxf(acc[i][2]  + bc[2],  0.f);
            o0.w = fmaxf(acc[i][3]  + bc[3],  0.f);
            o1.x = fmaxf(acc[i][4]  + bc[4],  0.f);
            o1.y = fmaxf(acc[i][5]  + bc[5],  0.f);
            o1.z = fmaxf(acc[i][6]  + bc[6],  0.f);
            o1.w = fmaxf(acc[i][7]  + bc[7],  0.f);
            o2.x = fmaxf(acc[i][8]  + bc[8],  0.f);
            o2.y = fmaxf(acc[i][9]  + bc[9],  0.f);
            o2.z = fmaxf(acc[i][10] + bc[10], 0.f);
            o2.w = fmaxf(acc[i][11] + bc[11], 0.f);
            float* po = out + (long long)r * HF + j0;
            *(float4*)(po + 0) = o0;
            *(float4*)(po + 4) = o1;
            *(float4*)(po + 8) = o2;
        }
    }
}

// ---------------- segment max pool (batch sorted) ----------------
#define POOL_CHUNK 128
__global__ void pool_kernel(const float* __restrict__ h, const int* __restrict__ batch,
                            unsigned* __restrict__ g, int N) {
    int j = threadIdx.x;
    if (j >= HF) return;
    int n0 = blockIdx.x * POOL_CHUNK;
    int end = n0 + POOL_CHUNK;
    if (end > N) end = N;
    float cur = 0.0f;
    int curb = -1;
    for (int n = n0; n < end; n++) {
        int b = batch[n];
        float v = h[(long long)n * HF + j];
        if (b != curb) {
            if (curb >= 0) atomicMax(&g[curb * HF + j], __float_as_uint(cur));
            curb = b;
            cur = v;
        } else {
            cur = fmaxf(cur, v);
        }
    }
    if (curb >= 0) atomicMax(&g[curb * HF + j], __float_as_uint(cur));
}

// ---------------- final MLP ----------------
__global__ void mlp_kernel(const unsigned* __restrict__ g, const float* __restrict__ lin1_w,
                           const float* __restrict__ lin1_b, const float* __restrict__ lin2_w,
                           const float* __restrict__ lin2_b, float* __restrict__ out) {
    int gi = threadIdx.x;
    if (gi >= GG) return;
    float h5[5];
#pragma unroll
    for (int hh = 0; hh < 5; hh++) {
        float acc = lin1_b[hh];
#pragma unroll 8
        for (int k = 0; k < HF; k++)
            acc = fmaf(__uint_as_float(g[gi * HF + k]), lin1_w[k * 5 + hh], acc);
        h5[hh] = fmaxf(acc, 0.0f);
    }
    float o = lin2_b[0];
#pragma unroll
    for (int hh = 0; hh < 5; hh++) o = fmaf(h5[hh], lin2_w[hh * 1 + 0], o);
    out[gi] = o;
}

extern "C" void kernel_launch(void* const* d_in, const int* in_sizes, int n_in,
                              void* d_out, int out_size, void* d_ws, size_t ws_size,
                              hipStream_t stream) {
    const float* x     = (const float*)d_in[0];
    const int*   ei    = (const int*)d_in[1];
    const int*   batch = (const int*)d_in[2];
    const float* W[3][3];
    const float* B[3][3];
    for (int l = 0; l < 3; l++) {
        for (int t = 0; t < 3; t++) W[l][t] = (const float*)d_in[3 + l * 6 + t];
        for (int t = 0; t < 3; t++) B[l][t] = (const float*)d_in[3 + l * 6 + 3 + t];
    }
    const float* lin1_w = (const float*)d_in[21];
    const float* lin1_b = (const float*)d_in[22];
    const float* lin2_w = (const float*)d_in[23];
    const float* lin2_b = (const float*)d_in[24];

    const int N = in_sizes[0] / HF;
    const int E = in_sizes[1] / 2;

    // workspace layout
    float* hA      = (float*)d_ws;
    float* hB      = hA + (long long)N * HF;
    float* agg_sd  = hB + (long long)N * HF;
    float* agg_ds  = agg_sd + (long long)N * HF;
    int*   cnt_dst = (int*)(agg_ds + (long long)N * HF);
    int*   cnt_src = cnt_dst + N;
    int*   off_dst = cnt_src + N;           // N+1
    int*   off_src = off_dst + (N + 1);     // N+1
    int*   cur_dst = off_src + (N + 1);
    int*   cur_src = cur_dst + N;
    int*   nbr_dst = cur_src + N;           // E
    int*   nbr_src = nbr_dst + E;           // E
    int*   bsum    = nbr_src + E;           // 2*SB
    int*   boff    = bsum + 2 * SB;         // 2*SB
    unsigned* g    = (unsigned*)(boff + 2 * SB);

    hipMemsetAsync(cnt_dst, 0, (size_t)2 * N * sizeof(int), stream);
    hipMemsetAsync(cur_dst, 0, (size_t)2 * N * sizeof(int), stream);
    hipMemsetAsync(g, 0, (size_t)GG * HF * sizeof(unsigned), stream);

    const int CH = (N + SB - 1) / SB;
    count_kernel<<<(E + 255) / 256, 256, 0, stream>>>(ei, cnt_dst, cnt_src, E);
    scan_phase1<<<dim3(SB, 2), 256, 0, stream>>>(cnt_dst, cnt_src, off_dst, off_src, bsum, N, CH);
    scan_phase2<<<2, SB, 0, stream>>>(bsum, boff, off_dst, off_src, N);
    scan_phase3<<<dim3((N + 255) / 256, 2), 256, 0, stream>>>(off_dst, off_src, boff, N, CH);
    fill_kernel<<<(E + 255) / 256, 256, 0, stream>>>(ei, off_dst, off_src,
                                                     cur_dst, cur_src, nbr_dst, nbr_src, E);

    const long long gather_threads = (long long)2 * N * 24;
    const int gather_blocks = (int)((gather_threads + 255) / 256);
    const int gemm_blocks = (N + BM - 1) / BM;
    const int pool_blocks = (N + POOL_CHUNK - 1) / POOL_CHUNK;

    const float* cur_in = x;
    float* outs[3] = { hA, hB, hA };
    for (int l = 0; l < 3; l++) {
        gather_kernel<<<gather_blocks, 256, 0, stream>>>(
            cur_in, off_dst, nbr_dst, off_src, nbr_src, agg_sd, agg_ds, N);
        sage_gemm_kernel<<<gemm_blocks, 256, 0, stream>>>(
            cur_in, agg_sd, agg_ds,
            W[l][0], W[l][1], W[l][2], B[l][0], B[l][1], B[l][2],
            outs[l], N);
        cur_in = outs[l];
    }

    pool_kernel<<<pool_blocks, 128, 0, stream>>>(outs[2], batch, g, N);
    mlp_kernel<<<1, 64, 0, stream>>>(g, lin1_w, lin1_b, lin2_w, lin2_b, (float*)d_out);
}